// Round 1
// baseline (3670.222 us; speedup 1.0000x reference)
//
#include <hip/hip_runtime.h>
#include <cstdint>

// ---------------------------------------------------------------------------
// ChartParser: span scores (3 fp32 GEMMs) + per-batch CKY DP + backtrack.
// B=64, S=256, D=H=1024. Output: int32 [2][B][S] (lefts then rights).
// ---------------------------------------------------------------------------

#define Bb 64
#define Ss 256
#define Dd 1024
#define Hh 1024

// ---------------------------------------------------------------------------
// Repack Wbil [1025,1025] into core [1024,1024] + last row + last col + corner
// so the big GEMM gets a 16B-aligned ldb.
// ---------------------------------------------------------------------------
__global__ __launch_bounds__(256) void repack_kernel(
    const float* __restrict__ Wbil, float* __restrict__ Wcore,
    float* __restrict__ brow, float* __restrict__ bcol,
    float* __restrict__ corner) {
  int idx = blockIdx.x * 256 + threadIdx.x;  // 0 .. 1048575
  int h = idx >> 10, g = idx & 1023;
  Wcore[idx] = Wbil[h * 1025 + g];
  if (h == 0) brow[g] = Wbil[1024 * 1025 + g];
  if (g == 0) bcol[h] = Wbil[h * 1025 + 1024];
  if (idx == 0) corner[0] = Wbil[1024 * 1025 + 1024];
}

// ---------------------------------------------------------------------------
// fp32 GEMM: C = act(A[M,K] * op(B) + bias[n] + rowAdd[m] + scal)
//   TRANSB=false: B is [K,N] ld=ldb.  TRANSB=true: B is [N,K] ld=ldb (C=A*B^T).
// Tile 128x128xBK8, 256 threads, 8x8 microtile (split-quad mapping: rows
// {ty*4+i, 64+ty*4+i}, cols {tx*4+j, 64+tx*4+j} -> conflict-free b128 LDS reads).
// M,N given by grid (grid.x=N/128, grid.y=M/128, grid.z=batch).
// ---------------------------------------------------------------------------
template <bool TRANSB, bool LEAKY>
__global__ __launch_bounds__(256) void gemm_kernel(
    const float* __restrict__ A, int lda, long long sA,
    const float* __restrict__ B, int ldb, long long sB,
    float* __restrict__ C, int ldc, long long sC,
    const float* __restrict__ bias, const float* __restrict__ rowAdd,
    long long sRow, const float* __restrict__ scal, int K) {
  const int bz = blockIdx.z;
  A += (long long)bz * sA;
  B += (long long)bz * sB;
  C += (long long)bz * sC;
  const int m0 = blockIdx.y * 128;
  const int n0 = blockIdx.x * 128;
  __shared__ float As[8][128];
  __shared__ float Bs[8][128];
  const int t = threadIdx.x;
  const int tx = t & 15, ty = t >> 4;
  const int arow = t >> 1, ak = (t & 1) * 4;

  float acc[8][8];
#pragma unroll
  for (int i = 0; i < 8; ++i)
#pragma unroll
    for (int j = 0; j < 8; ++j) acc[i][j] = 0.f;

  for (int k0 = 0; k0 < K; k0 += 8) {
    float4 av = *(const float4*)(A + (long long)(m0 + arow) * lda + (k0 + ak));
    float4 bv;
    int brow_nn = t >> 5, bn_nn = (t & 31) * 4;   // NN: 8 k-rows x 128 n
    int bn_t = t >> 1, bk_t = (t & 1) * 4;        // NT: 128 n-rows x 8 k
    if (!TRANSB) {
      bv = *(const float4*)(B + (long long)(k0 + brow_nn) * ldb + (n0 + bn_nn));
    } else {
      bv = *(const float4*)(B + (long long)(n0 + bn_t) * ldb + (k0 + bk_t));
    }
    __syncthreads();  // previous iteration's LDS reads must finish
    As[ak + 0][arow] = av.x;
    As[ak + 1][arow] = av.y;
    As[ak + 2][arow] = av.z;
    As[ak + 3][arow] = av.w;
    if (!TRANSB) {
      *(float4*)&Bs[brow_nn][bn_nn] = bv;
    } else {
      Bs[bk_t + 0][bn_t] = bv.x;
      Bs[bk_t + 1][bn_t] = bv.y;
      Bs[bk_t + 2][bn_t] = bv.z;
      Bs[bk_t + 3][bn_t] = bv.w;
    }
    __syncthreads();
#pragma unroll
    for (int k = 0; k < 8; ++k) {
      float4 a0 = *(const float4*)&As[k][ty * 4];
      float4 a1 = *(const float4*)&As[k][64 + ty * 4];
      float4 b0 = *(const float4*)&Bs[k][tx * 4];
      float4 b1 = *(const float4*)&Bs[k][64 + tx * 4];
      float a[8] = {a0.x, a0.y, a0.z, a0.w, a1.x, a1.y, a1.z, a1.w};
      float bb[8] = {b0.x, b0.y, b0.z, b0.w, b1.x, b1.y, b1.z, b1.w};
#pragma unroll
      for (int i = 0; i < 8; ++i)
#pragma unroll
        for (int j = 0; j < 8; ++j) acc[i][j] = fmaf(a[i], bb[j], acc[i][j]);
    }
  }

  const float sc_add = (scal != nullptr) ? scal[0] : 0.f;
#pragma unroll
  for (int ih = 0; ih < 2; ++ih) {
#pragma unroll
    for (int ii = 0; ii < 4; ++ii) {
      int row = m0 + ih * 64 + ty * 4 + ii;
      float radd = sc_add;
      if (rowAdd != nullptr) radd += rowAdd[(long long)bz * sRow + row];
#pragma unroll
      for (int jh = 0; jh < 2; ++jh) {
        int col = n0 + jh * 64 + tx * 4;
        float vv[4];
#pragma unroll
        for (int jj = 0; jj < 4; ++jj) {
          float x = acc[ih * 4 + ii][jh * 4 + jj] + radd;
          if (bias != nullptr) x += bias[col + jj];
          if (LEAKY) x = (x > 0.f) ? x : 0.1f * x;
          vv[jj] = x;
        }
        float4 v = make_float4(vv[0], vv[1], vv[2], vv[3]);
        *(float4*)(C + (long long)row * ldc + col) = v;
      }
    }
  }
}

// ---------------------------------------------------------------------------
// tmpb[i] = dot(lefts[i,:], Wbil[0:H, H]) + Wbil[H,H].  One wave per row.
// ---------------------------------------------------------------------------
__global__ __launch_bounds__(64) void colvec_kernel(
    const float* __restrict__ lefts, const float* __restrict__ bcol,
    const float* __restrict__ corner, float* __restrict__ tmpb) {
  int row = blockIdx.x;
  int lane = threadIdx.x;
  const float* a = lefts + (long long)row * Hh;
  float s = 0.f;
#pragma unroll
  for (int h = lane; h < Hh; h += 64) s = fmaf(a[h], bcol[h], s);
#pragma unroll
  for (int off = 32; off > 0; off >>= 1) s += __shfl_down(s, off, 64);
  if (lane == 0) tmpb[row] = s + corner[0];
}

// ---------------------------------------------------------------------------
// CKY + backtrack. One block per batch, 256 threads (thread = span start i).
// Chart stored diagonal-major: D[w*256+i] = chart[i][i+w] -> both DP operands
// are lane-coalesced. Split offsets (m) in uint8, same layout. After the DP,
// thread 0 replicates the reference's stack backtrack exactly (pop order,
// conditional-overwrite push semantics).
// ---------------------------------------------------------------------------
__global__ __launch_bounds__(256) void cky_kernel(
    const float* __restrict__ scores,  // [64][256][256]
    float* __restrict__ Dws,           // [64][256][256] diag-major
    uint8_t* __restrict__ Sws,         // [64][256][256] diag-major
    int* __restrict__ out)             // [2][64][256] int32
{
  const int b = blockIdx.x;
  const int i = threadIdx.x;
  const int n = Ss;
  const float* sc = scores + (long long)b * n * n;
  float* D = Dws + (long long)b * n * n;
  uint8_t* SP = Sws + (long long)b * n * n;
  __shared__ int stk[256];

  // zero output rows for this batch (slot n-1 must read 0, like torch.zeros)
  out[b * n + i] = 0;
  out[Bb * n + b * n + i] = 0;
  D[i] = 0.f;  // width-0 diagonal: singleton spans score 0
  __syncthreads();

  for (int w = 1; w < n; ++w) {
    const int j = i + w;
    if (j < n) {
      const float* Dl = D + i;            // D[m*256 + i]
      const float* Dr = D + i + 1;        // D[(w-1-m)*256 + i + m + 1]
      float best = -3.0e38f;
      int bm = 0;
#pragma unroll 4
      for (int m = 0; m < w; ++m) {
        float c = Dl[m * n] + Dr[(w - 1 - m) * n + m];
        if (c > best) {  // strict > keeps FIRST max, matching jnp.argmax
          best = c;
          bm = m;
        }
      }
      D[w * n + i] = sc[i * n + j] + best;
      SP[w * n + i] = (uint8_t)bm;
    }
    __syncthreads();
  }

  if (i == 0) {
    int top = 0;
    stk[top++] = (0 << 16) | (n - 1);
    int cnt = 0;
    for (int step = 0; step < n - 1; ++step) {
      if (top > 0) {
        int ij = stk[--top];
        int ii = ij >> 16, jj = ij & 0xffff;
        out[b * n + cnt] = ii;
        out[Bb * n + b * n + cnt] = jj;
        ++cnt;
        int s = ii + (int)SP[(jj - ii) * n + ii];
        stk[top] = (ii << 16) | s;
        if (s > ii) ++top;
        stk[top] = ((s + 1) << 16) | jj;
        if (jj > s + 1) ++top;
      }
    }
  }
}

// ---------------------------------------------------------------------------
// Launch
// ---------------------------------------------------------------------------
extern "C" void kernel_launch(void* const* d_in, const int* in_sizes, int n_in,
                              void* d_out, int out_size, void* d_ws,
                              size_t ws_size, hipStream_t stream) {
  const float* X = (const float*)d_in[0];     // [64,256,1024]
  const float* Wl = (const float*)d_in[2];    // [1024,1024]
  const float* bl = (const float*)d_in[3];    // [1024]
  const float* Wr = (const float*)d_in[4];
  const float* br = (const float*)d_in[5];
  const float* Wbil = (const float*)d_in[6];  // [1025,1025]
  const float* bbil = (const float*)d_in[7];  // scalar
  int* out = (int*)d_out;

  // workspace layout (floats)
  float* ws = (float*)d_ws;
  const long long NROWS = (long long)Bb * Ss;      // 16384
  float* lefts = ws;                               // 16384x1024
  float* rights = lefts + NROWS * Hh;              // 16384x1024
  float* tmpA = rights + NROWS * Hh;               // 16384x1024
  float* scoresP = tmpA + NROWS * Hh;              // 64x256x256
  float* Dp = scoresP + (long long)Bb * Ss * Ss;   // 64x256x256
  float* tmpb = Dp + (long long)Bb * Ss * Ss;      // 16384
  float* Wcore = tmpb + NROWS;                     // 1024x1024
  float* browp = Wcore + (long long)Dd * Hh;       // 1024
  float* bcolp = browp + Hh;                       // 1024
  float* cornerp = bcolp + Hh;                     // 1
  uint8_t* SPp = (uint8_t*)(cornerp + 3);          // 64x256x256 u8 (4B aligned)

  repack_kernel<<<dim3(4096), dim3(256), 0, stream>>>(Wbil, Wcore, browp,
                                                      bcolp, cornerp);

  dim3 g1(Hh / 128, NROWS / 128, 1);  // (8,128,1)
  gemm_kernel<false, true><<<g1, 256, 0, stream>>>(
      X, Dd, 0LL, Wl, Hh, 0LL, lefts, Hh, 0LL, bl, nullptr, 0LL, nullptr, Dd);
  gemm_kernel<false, true><<<g1, 256, 0, stream>>>(
      X, Dd, 0LL, Wr, Hh, 0LL, rights, Hh, 0LL, br, nullptr, 0LL, nullptr, Dd);

  colvec_kernel<<<dim3(NROWS), dim3(64), 0, stream>>>(lefts, bcolp, cornerp,
                                                      tmpb);

  gemm_kernel<false, false><<<g1, 256, 0, stream>>>(
      lefts, Hh, 0LL, Wcore, Hh, 0LL, tmpA, Hh, 0LL, browp, nullptr, 0LL,
      nullptr, Hh);

  dim3 g3(Ss / 128, Ss / 128, Bb);  // (2,2,64)
  gemm_kernel<true, false><<<g3, 256, 0, stream>>>(
      tmpA, Hh, (long long)Ss * Hh, rights, Hh, (long long)Ss * Hh, scoresP,
      Ss, (long long)Ss * Ss, nullptr, tmpb, (long long)Ss, bbil, Hh);

  cky_kernel<<<dim3(Bb), dim3(256), 0, stream>>>(scoresP, Dp, SPp, out);
}

// Round 2
// 2321.880 us; speedup vs baseline: 1.5807x; 1.5807x over previous
//
#include <hip/hip_runtime.h>
#include <cstdint>

// ---------------------------------------------------------------------------
// ChartParser: span scores (3 fp32 GEMMs) + per-batch CKY DP + backtrack.
// B=64, S=256, D=H=1024. Output: int32 [2][B][S] (lefts then rights).
// Round 2: CKY chart moved to LDS (packed triangular, 131.5 KB) + m-loop
// split across the 4 waves with a first-max-preserving combine.
// ---------------------------------------------------------------------------

#define Bb 64
#define Ss 256
#define Dd 1024
#define Hh 1024

// ---------------------------------------------------------------------------
// Repack Wbil [1025,1025] into core [1024,1024] + last row + last col + corner
// so the big GEMM gets a 16B-aligned ldb.
// ---------------------------------------------------------------------------
__global__ __launch_bounds__(256) void repack_kernel(
    const float* __restrict__ Wbil, float* __restrict__ Wcore,
    float* __restrict__ brow, float* __restrict__ bcol,
    float* __restrict__ corner) {
  int idx = blockIdx.x * 256 + threadIdx.x;  // 0 .. 1048575
  int h = idx >> 10, g = idx & 1023;
  Wcore[idx] = Wbil[h * 1025 + g];
  if (h == 0) brow[g] = Wbil[1024 * 1025 + g];
  if (g == 0) bcol[h] = Wbil[h * 1025 + 1024];
  if (idx == 0) corner[0] = Wbil[1024 * 1025 + 1024];
}

// ---------------------------------------------------------------------------
// fp32 GEMM: C = act(A[M,K] * op(B) + bias[n] + rowAdd[m] + scal)
//   TRANSB=false: B is [K,N] ld=ldb.  TRANSB=true: B is [N,K] ld=ldb (C=A*B^T).
// Tile 128x128xBK8, 256 threads, 8x8 microtile (split-quad mapping: rows
// {ty*4+i, 64+ty*4+i}, cols {tx*4+j, 64+tx*4+j} -> conflict-free b128 LDS reads).
// M,N given by grid (grid.x=N/128, grid.y=M/128, grid.z=batch).
// ---------------------------------------------------------------------------
template <bool TRANSB, bool LEAKY>
__global__ __launch_bounds__(256) void gemm_kernel(
    const float* __restrict__ A, int lda, long long sA,
    const float* __restrict__ B, int ldb, long long sB,
    float* __restrict__ C, int ldc, long long sC,
    const float* __restrict__ bias, const float* __restrict__ rowAdd,
    long long sRow, const float* __restrict__ scal, int K) {
  const int bz = blockIdx.z;
  A += (long long)bz * sA;
  B += (long long)bz * sB;
  C += (long long)bz * sC;
  const int m0 = blockIdx.y * 128;
  const int n0 = blockIdx.x * 128;
  __shared__ float As[8][128];
  __shared__ float Bs[8][128];
  const int t = threadIdx.x;
  const int tx = t & 15, ty = t >> 4;
  const int arow = t >> 1, ak = (t & 1) * 4;

  float acc[8][8];
#pragma unroll
  for (int i = 0; i < 8; ++i)
#pragma unroll
    for (int j = 0; j < 8; ++j) acc[i][j] = 0.f;

  for (int k0 = 0; k0 < K; k0 += 8) {
    float4 av = *(const float4*)(A + (long long)(m0 + arow) * lda + (k0 + ak));
    float4 bv;
    int brow_nn = t >> 5, bn_nn = (t & 31) * 4;   // NN: 8 k-rows x 128 n
    int bn_t = t >> 1, bk_t = (t & 1) * 4;        // NT: 128 n-rows x 8 k
    if (!TRANSB) {
      bv = *(const float4*)(B + (long long)(k0 + brow_nn) * ldb + (n0 + bn_nn));
    } else {
      bv = *(const float4*)(B + (long long)(n0 + bn_t) * ldb + (k0 + bk_t));
    }
    __syncthreads();  // previous iteration's LDS reads must finish
    As[ak + 0][arow] = av.x;
    As[ak + 1][arow] = av.y;
    As[ak + 2][arow] = av.z;
    As[ak + 3][arow] = av.w;
    if (!TRANSB) {
      *(float4*)&Bs[brow_nn][bn_nn] = bv;
    } else {
      Bs[bk_t + 0][bn_t] = bv.x;
      Bs[bk_t + 1][bn_t] = bv.y;
      Bs[bk_t + 2][bn_t] = bv.z;
      Bs[bk_t + 3][bn_t] = bv.w;
    }
    __syncthreads();
#pragma unroll
    for (int k = 0; k < 8; ++k) {
      float4 a0 = *(const float4*)&As[k][ty * 4];
      float4 a1 = *(const float4*)&As[k][64 + ty * 4];
      float4 b0 = *(const float4*)&Bs[k][tx * 4];
      float4 b1 = *(const float4*)&Bs[k][64 + tx * 4];
      float a[8] = {a0.x, a0.y, a0.z, a0.w, a1.x, a1.y, a1.z, a1.w};
      float bb[8] = {b0.x, b0.y, b0.z, b0.w, b1.x, b1.y, b1.z, b1.w};
#pragma unroll
      for (int i = 0; i < 8; ++i)
#pragma unroll
        for (int j = 0; j < 8; ++j) acc[i][j] = fmaf(a[i], bb[j], acc[i][j]);
    }
  }

  const float sc_add = (scal != nullptr) ? scal[0] : 0.f;
#pragma unroll
  for (int ih = 0; ih < 2; ++ih) {
#pragma unroll
    for (int ii = 0; ii < 4; ++ii) {
      int row = m0 + ih * 64 + ty * 4 + ii;
      float radd = sc_add;
      if (rowAdd != nullptr) radd += rowAdd[(long long)bz * sRow + row];
#pragma unroll
      for (int jh = 0; jh < 2; ++jh) {
        int col = n0 + jh * 64 + tx * 4;
        float vv[4];
#pragma unroll
        for (int jj = 0; jj < 4; ++jj) {
          float x = acc[ih * 4 + ii][jh * 4 + jj] + radd;
          if (bias != nullptr) x += bias[col + jj];
          if (LEAKY) x = (x > 0.f) ? x : 0.1f * x;
          vv[jj] = x;
        }
        float4 v = make_float4(vv[0], vv[1], vv[2], vv[3]);
        *(float4*)(C + (long long)row * ldc + col) = v;
      }
    }
  }
}

// ---------------------------------------------------------------------------
// tmpb[i] = dot(lefts[i,:], Wbil[0:H, H]) + Wbil[H,H].  One wave per row.
// ---------------------------------------------------------------------------
__global__ __launch_bounds__(64) void colvec_kernel(
    const float* __restrict__ lefts, const float* __restrict__ bcol,
    const float* __restrict__ corner, float* __restrict__ tmpb) {
  int row = blockIdx.x;
  int lane = threadIdx.x;
  const float* a = lefts + (long long)row * Hh;
  float s = 0.f;
#pragma unroll
  for (int h = lane; h < Hh; h += 64) s = fmaf(a[h], bcol[h], s);
#pragma unroll
  for (int off = 32; off > 0; off >>= 1) s += __shfl_down(s, off, 64);
  if (lane == 0) tmpb[row] = s + corner[0];
}

// ---------------------------------------------------------------------------
// CKY + backtrack. One block per batch, 256 threads (4 waves).
// Chart in LDS, packed triangular diag-major: Dch[off(w)+i] = chart[i][i+w],
// off(w) = w*n - w*(w-1)/2 (32896 floats = 131.5 KB, fits gfx950's 160 KB).
// Both DP operand streams are lane-stride-1 (2-way bank aliasing = free).
// The m-loop is split across the 4 waves (wave q takes m-segment
// [q*ceil(w/4), ...)); partial (best, argm) per (q,i) goes to LDS; a 4-way
// ascending-q strict-> combine preserves jnp.argmax first-max semantics.
// Split table (uint8, packed triangular) in global; thread 0 then replicates
// the reference's stack backtrack exactly.
// ---------------------------------------------------------------------------
__global__ __launch_bounds__(256) void cky_kernel(
    const float* __restrict__ scores,  // [64][256][256]
    uint8_t* __restrict__ Sws,         // [64][32896] packed triangular
    int* __restrict__ out)             // [2][64][256] int32
{
  const int b = blockIdx.x;
  const int t = threadIdx.x;
  const int lane = t & 63;
  const int q = t >> 6;  // wave id
  const int n = Ss;
  const float* sc = scores + (long long)b * n * n;
  uint8_t* SP = Sws + (long long)b * 32896;

  __shared__ float Dch[32896];   // packed triangular chart (131584 B)
  __shared__ float pv[4][256];   // per-wave partial best
  __shared__ uint8_t pmv[4][256];// per-wave partial argm (absolute m)
  __shared__ int stk[256];

  // zero output rows for this batch (slot n-1 must read 0, like torch.zeros)
  out[b * n + t] = 0;
  out[Bb * n + b * n + t] = 0;
  Dch[t] = 0.f;  // width-0 diagonal: singleton spans score 0
  __syncthreads();

  int offw = n;  // off(1)
  for (int w = 1; w < n; ++w) {
    const int nv = n - w;  // number of valid spans at this width
    // prefetch this thread's score (used in combine) to overlap with partials
    float scv = 0.f;
    if (t < nv) scv = sc[t * (n + 1) + w];

    // ---- partial phase: wave q covers m in [ml, mh) ----
    const int w4 = (w + 3) >> 2;
    const int ml = q * w4;
    const int mh = (w < ml + w4) ? w : (ml + w4);
#pragma unroll
    for (int c = 0; c < 4; ++c) {
      const int ii = c * 64 + lane;
      if (ii < nv) {
        float best = -3.0e38f;
        int bmv = 0;
        if (ml < mh) {
          int al = ml * n - ((ml * (ml - 1)) >> 1) + ii;  // off(ml)+ii
          const int kr = w - 1 - ml;
          int ar = kr * n - ((kr * (kr - 1)) >> 1) + ii + ml + 1;
          int dl = n - ml;          // al step
          int dr = n - w + ml + 1;  // ar step (negative direction)
#pragma unroll 4
          for (int m = ml; m < mh; ++m) {
            float cnd = Dch[al] + Dch[ar];
            if (cnd > best) {  // strict > keeps FIRST (lowest-m) max
              best = cnd;
              bmv = m;
            }
            al += dl;
            ar -= dr;
            --dl;
            ++dr;
          }
        }
        pv[q][ii] = best;
        pmv[q][ii] = (uint8_t)bmv;
      }
    }
    __syncthreads();

    // ---- combine phase: thread t = span start i ----
    if (t < nv) {
      float best = pv[0][t];
      int bm = pmv[0][t];
#pragma unroll
      for (int q2 = 1; q2 < 4; ++q2) {
        float v = pv[q2][t];
        if (v > best) {  // ascending q, strict > -> lowest-m max wins
          best = v;
          bm = pmv[q2][t];
        }
      }
      Dch[offw + t] = scv + best;
      SP[offw + t] = (uint8_t)bm;
    }
    __syncthreads();
    offw += n - w;
  }

  if (t == 0) {
    int top = 0;
    stk[top++] = (0 << 16) | (n - 1);
    int cnt = 0;
    for (int step = 0; step < n - 1; ++step) {
      if (top > 0) {
        int ij = stk[--top];
        int ii = ij >> 16, jj = ij & 0xffff;
        out[b * n + cnt] = ii;
        out[Bb * n + b * n + cnt] = jj;
        ++cnt;
        int k = jj - ii;
        int s = ii + (int)SP[k * n - ((k * (k - 1)) >> 1) + ii];
        stk[top] = (ii << 16) | s;
        if (s > ii) ++top;
        stk[top] = ((s + 1) << 16) | jj;
        if (jj > s + 1) ++top;
      }
    }
  }
}

// ---------------------------------------------------------------------------
// Launch
// ---------------------------------------------------------------------------
extern "C" void kernel_launch(void* const* d_in, const int* in_sizes, int n_in,
                              void* d_out, int out_size, void* d_ws,
                              size_t ws_size, hipStream_t stream) {
  const float* X = (const float*)d_in[0];     // [64,256,1024]
  const float* Wl = (const float*)d_in[2];    // [1024,1024]
  const float* bl = (const float*)d_in[3];    // [1024]
  const float* Wr = (const float*)d_in[4];
  const float* br = (const float*)d_in[5];
  const float* Wbil = (const float*)d_in[6];  // [1025,1025]
  const float* bbil = (const float*)d_in[7];  // scalar
  int* out = (int*)d_out;

  // workspace layout (floats)
  float* ws = (float*)d_ws;
  const long long NROWS = (long long)Bb * Ss;      // 16384
  float* lefts = ws;                               // 16384x1024
  float* rights = lefts + NROWS * Hh;              // 16384x1024
  float* tmpA = rights + NROWS * Hh;               // 16384x1024
  float* scoresP = tmpA + NROWS * Hh;              // 64x256x256
  float* tmpb = scoresP + (long long)Bb * Ss * Ss; // 16384
  float* Wcore = tmpb + NROWS;                     // 1024x1024
  float* browp = Wcore + (long long)Dd * Hh;       // 1024
  float* bcolp = browp + Hh;                       // 1024
  float* cornerp = bcolp + Hh;                     // 1
  uint8_t* SPp = (uint8_t*)(cornerp + 3);          // 64x32896 u8 (4B aligned)

  repack_kernel<<<dim3(4096), dim3(256), 0, stream>>>(Wbil, Wcore, browp,
                                                      bcolp, cornerp);

  dim3 g1(Hh / 128, NROWS / 128, 1);  // (8,128,1)
  gemm_kernel<false, true><<<g1, 256, 0, stream>>>(
      X, Dd, 0LL, Wl, Hh, 0LL, lefts, Hh, 0LL, bl, nullptr, 0LL, nullptr, Dd);
  gemm_kernel<false, true><<<g1, 256, 0, stream>>>(
      X, Dd, 0LL, Wr, Hh, 0LL, rights, Hh, 0LL, br, nullptr, 0LL, nullptr, Dd);

  colvec_kernel<<<dim3(NROWS), dim3(64), 0, stream>>>(lefts, bcolp, cornerp,
                                                      tmpb);

  gemm_kernel<false, false><<<g1, 256, 0, stream>>>(
      lefts, Hh, 0LL, Wcore, Hh, 0LL, tmpA, Hh, 0LL, browp, nullptr, 0LL,
      nullptr, Hh);

  dim3 g3(Ss / 128, Ss / 128, Bb);  // (2,2,64)
  gemm_kernel<true, false><<<g3, 256, 0, stream>>>(
      tmpA, Hh, (long long)Ss * Hh, rights, Hh, (long long)Ss * Hh, scoresP,
      Ss, (long long)Ss * Ss, nullptr, tmpb, (long long)Ss, bbil, Hh);

  cky_kernel<<<dim3(Bb), dim3(256), 0, stream>>>(scoresP, SPp, out);
}

// Round 3
// 2129.227 us; speedup vs baseline: 1.7237x; 1.0905x over previous
//
#include <hip/hip_runtime.h>
#include <cstdint>

// ---------------------------------------------------------------------------
// ChartParser: span scores (3 fp32 GEMMs) + per-batch CKY DP + backtrack.
// B=64, S=256, D=H=1024. Output: int32 [2][B][S] (lefts then rights).
// Round 3: (a) CKY with 1024 threads (4 waves/SIMD for LDS latency hiding) +
// adaptive m-group split (4/8/16-way by diagonal length) + LDS backtrack;
// (b) GEMM with double-buffered LDS (one barrier per K-iter).
// ---------------------------------------------------------------------------

#define Bb 64
#define Ss 256
#define Dd 1024
#define Hh 1024

// ---------------------------------------------------------------------------
// Repack Wbil [1025,1025] into core [1024,1024] + last row + last col + corner
// ---------------------------------------------------------------------------
__global__ __launch_bounds__(256) void repack_kernel(
    const float* __restrict__ Wbil, float* __restrict__ Wcore,
    float* __restrict__ brow, float* __restrict__ bcol,
    float* __restrict__ corner) {
  int idx = blockIdx.x * 256 + threadIdx.x;  // 0 .. 1048575
  int h = idx >> 10, g = idx & 1023;
  Wcore[idx] = Wbil[h * 1025 + g];
  if (h == 0) brow[g] = Wbil[1024 * 1025 + g];
  if (g == 0) bcol[h] = Wbil[h * 1025 + 1024];
  if (idx == 0) corner[0] = Wbil[1024 * 1025 + 1024];
}

// ---------------------------------------------------------------------------
// fp32 GEMM: C = act(A[M,K] * op(B) + bias[n] + rowAdd[m] + scal)
// 128x128xBK8 tile, 256 threads, 8x8 microtile, DOUBLE-BUFFERED LDS:
// per iter: prefetch next tile to regs | compute from LDS[cur] | store to
// LDS[cur^1] | ONE barrier. (Barrier drain of cur-buffer reads is implied by
// the compiler's lgkmcnt(0)-before-s_barrier.)
// ---------------------------------------------------------------------------
template <bool TRANSB, bool LEAKY>
__global__ __launch_bounds__(256) void gemm_kernel(
    const float* __restrict__ A, int lda, long long sA,
    const float* __restrict__ B, int ldb, long long sB,
    float* __restrict__ C, int ldc, long long sC,
    const float* __restrict__ bias, const float* __restrict__ rowAdd,
    long long sRow, const float* __restrict__ scal, int K) {
  const int bz = blockIdx.z;
  A += (long long)bz * sA;
  B += (long long)bz * sB;
  C += (long long)bz * sC;
  const int m0 = blockIdx.y * 128;
  const int n0 = blockIdx.x * 128;
  __shared__ float As[2][8][128];
  __shared__ float Bs[2][8][128];
  const int t = threadIdx.x;
  const int tx = t & 15, ty = t >> 4;
  const int arow = t >> 1, ak = (t & 1) * 4;
  const int brow_nn = t >> 5, bn_nn = (t & 31) * 4;  // NN: 8 k-rows x 128 n
  const int bn_t = t >> 1, bk_t = (t & 1) * 4;       // NT: 128 n-rows x 8 k

  float acc[8][8];
#pragma unroll
  for (int i = 0; i < 8; ++i)
#pragma unroll
    for (int j = 0; j < 8; ++j) acc[i][j] = 0.f;

  // prologue: stage k0=0 into buffer 0
  {
    float4 av = *(const float4*)(A + (long long)(m0 + arow) * lda + ak);
    float4 bv;
    if (!TRANSB)
      bv = *(const float4*)(B + (long long)brow_nn * ldb + (n0 + bn_nn));
    else
      bv = *(const float4*)(B + (long long)(n0 + bn_t) * ldb + bk_t);
    As[0][ak + 0][arow] = av.x;
    As[0][ak + 1][arow] = av.y;
    As[0][ak + 2][arow] = av.z;
    As[0][ak + 3][arow] = av.w;
    if (!TRANSB) {
      *(float4*)&Bs[0][brow_nn][bn_nn] = bv;
    } else {
      Bs[0][bk_t + 0][bn_t] = bv.x;
      Bs[0][bk_t + 1][bn_t] = bv.y;
      Bs[0][bk_t + 2][bn_t] = bv.z;
      Bs[0][bk_t + 3][bn_t] = bv.w;
    }
  }
  __syncthreads();

  int cur = 0;
  for (int k0 = 0; k0 < K; k0 += 8) {
    float4 av, bv;
    const bool more = (k0 + 8) < K;
    if (more) {
      av = *(const float4*)(A + (long long)(m0 + arow) * lda + (k0 + 8 + ak));
      if (!TRANSB)
        bv = *(const float4*)(B + (long long)(k0 + 8 + brow_nn) * ldb +
                              (n0 + bn_nn));
      else
        bv = *(const float4*)(B + (long long)(n0 + bn_t) * ldb +
                              (k0 + 8 + bk_t));
    }
#pragma unroll
    for (int k = 0; k < 8; ++k) {
      float4 a0 = *(const float4*)&As[cur][k][ty * 4];
      float4 a1 = *(const float4*)&As[cur][k][64 + ty * 4];
      float4 b0 = *(const float4*)&Bs[cur][k][tx * 4];
      float4 b1 = *(const float4*)&Bs[cur][k][64 + tx * 4];
      float a[8] = {a0.x, a0.y, a0.z, a0.w, a1.x, a1.y, a1.z, a1.w};
      float bb[8] = {b0.x, b0.y, b0.z, b0.w, b1.x, b1.y, b1.z, b1.w};
#pragma unroll
      for (int i = 0; i < 8; ++i)
#pragma unroll
        for (int j = 0; j < 8; ++j) acc[i][j] = fmaf(a[i], bb[j], acc[i][j]);
    }
    if (more) {
      const int nxt = cur ^ 1;
      As[nxt][ak + 0][arow] = av.x;
      As[nxt][ak + 1][arow] = av.y;
      As[nxt][ak + 2][arow] = av.z;
      As[nxt][ak + 3][arow] = av.w;
      if (!TRANSB) {
        *(float4*)&Bs[nxt][brow_nn][bn_nn] = bv;
      } else {
        Bs[nxt][bk_t + 0][bn_t] = bv.x;
        Bs[nxt][bk_t + 1][bn_t] = bv.y;
        Bs[nxt][bk_t + 2][bn_t] = bv.z;
        Bs[nxt][bk_t + 3][bn_t] = bv.w;
      }
    }
    __syncthreads();
    cur ^= 1;
  }

  const float sc_add = (scal != nullptr) ? scal[0] : 0.f;
#pragma unroll
  for (int ih = 0; ih < 2; ++ih) {
#pragma unroll
    for (int ii = 0; ii < 4; ++ii) {
      int row = m0 + ih * 64 + ty * 4 + ii;
      float radd = sc_add;
      if (rowAdd != nullptr) radd += rowAdd[(long long)bz * sRow + row];
#pragma unroll
      for (int jh = 0; jh < 2; ++jh) {
        int col = n0 + jh * 64 + tx * 4;
        float vv[4];
#pragma unroll
        for (int jj = 0; jj < 4; ++jj) {
          float x = acc[ih * 4 + ii][jh * 4 + jj] + radd;
          if (bias != nullptr) x += bias[col + jj];
          if (LEAKY) x = (x > 0.f) ? x : 0.1f * x;
          vv[jj] = x;
        }
        float4 v = make_float4(vv[0], vv[1], vv[2], vv[3]);
        *(float4*)(C + (long long)row * ldc + col) = v;
      }
    }
  }
}

// ---------------------------------------------------------------------------
// tmpb[i] = dot(lefts[i,:], Wbil[0:H, H]) + Wbil[H,H].  One wave per row.
// ---------------------------------------------------------------------------
__global__ __launch_bounds__(64) void colvec_kernel(
    const float* __restrict__ lefts, const float* __restrict__ bcol,
    const float* __restrict__ corner, float* __restrict__ tmpb) {
  int row = blockIdx.x;
  int lane = threadIdx.x;
  const float* a = lefts + (long long)row * Hh;
  float s = 0.f;
#pragma unroll
  for (int h = lane; h < Hh; h += 64) s = fmaf(a[h], bcol[h], s);
#pragma unroll
  for (int off = 32; off > 0; off >>= 1) s += __shfl_down(s, off, 64);
  if (lane == 0) tmpb[row] = s + corner[0];
}

// ---------------------------------------------------------------------------
// CKY + backtrack. One block per batch, 1024 threads (16 waves = 4/SIMD for
// LDS latency hiding). Chart in LDS, packed triangular diag-major:
// Dch[off(w)+i], off(w) = w*n - w*(w-1)/2. Adaptive m-split: the 1024 threads
// are G m-groups x T i-threads with (G,T) = (4,256)/(8,128)/(16,64) chosen so
// T >= nv — every thread stays busy at every width. Partials (best, argm) per
// (g,i) go to LDS; ascending-g strict-> combine preserves jnp.argmax
// first-max semantics. SP (uint8 splits) streams to global during the DP,
// then is copied into the dead chart's LDS for the serial backtrack chase.
// ---------------------------------------------------------------------------
__global__ __launch_bounds__(1024) void cky_kernel(
    const float* __restrict__ scores,  // [64][256][256]
    uint8_t* __restrict__ Sws,         // [64][32896] packed triangular
    int* __restrict__ out)             // [2][64][256] int32
{
  const int b = blockIdx.x;
  const int t = threadIdx.x;
  const int n = Ss;
  const float* sc = scores + (long long)b * n * n;
  uint8_t* SP = Sws + (long long)b * 32896;

  __shared__ float Dch[32896];    // packed triangular chart (131584 B)
  __shared__ float pv[1024];      // partial best,   indexed g*T + u
  __shared__ uint8_t pmv[1024];   // partial argm (absolute m)
  __shared__ int stk[256];

  if (t < n) {
    out[b * n + t] = 0;  // slot n-1 must stay 0 (torch.zeros semantics)
    out[Bb * n + b * n + t] = 0;
    Dch[t] = 0.f;  // width-0 diagonal: singleton spans score 0
  }
  __syncthreads();

  int offw = n;  // off(1)
  for (int w = 1; w < n; ++w) {
    const int nv = n - w;
    // adaptive split: T = smallest of {256,128,64} with T >= nv
    const int lgT = (nv > 128) ? 8 : ((nv > 64) ? 7 : 6);
    const int T = 1 << lgT;
    const int G = 1024 >> lgT;
    const int g = t >> lgT;
    const int u = t & (T - 1);

    // prefetch this thread's score (combine input) to overlap with partials
    float scv = 0.f;
    if (t < nv) scv = sc[t * (n + 1) + w];

    // ---- partial phase: group g covers m in [ml, mh) for span start i=u ---
    const int wG = (w + G - 1) >> (10 - lgT);  // ceil(w/G)
    const int ml = g * wG;
    const int mh = (w < ml + wG) ? w : (ml + wG);
    float best = -3.0e38f;
    int bmv = 0;
    if (u < nv && ml < mh) {
      int al = ml * n - ((ml * (ml - 1)) >> 1) + u;  // off(ml)+i
      const int kr = w - 1 - ml;
      int ar = kr * n - ((kr * (kr - 1)) >> 1) + u + ml + 1;
      int dl = n - ml;          // al step (decreasing)
      int dr = n - w + ml + 1;  // ar step (increasing, subtracted)
#pragma unroll 4
      for (int m = ml; m < mh; ++m) {
        float c = Dch[al] + Dch[ar];
        if (c > best) {  // strict > keeps FIRST (lowest-m) max
          best = c;
          bmv = m;
        }
        al += dl;
        ar -= dr;
        --dl;
        ++dr;
      }
    }
    pv[t] = best;
    pmv[t] = (uint8_t)bmv;
    __syncthreads();

    // ---- combine phase: thread t = span start i (t < nv <= T) ----
    if (t < nv) {
      float bb = pv[t];
      int bm = pmv[t];
      for (int g2 = 1; g2 < G; ++g2) {  // ascending g + strict > = first max
        float v = pv[g2 * T + t];
        if (v > bb) {
          bb = v;
          bm = pmv[g2 * T + t];
        }
      }
      Dch[offw + t] = scv + bb;
      SP[offw + t] = (uint8_t)bm;
    }
    __syncthreads();
    offw += nv;
  }

  // ---- backtrack: copy SP into the dead chart's LDS, then serial chase ----
  uint8_t* spl = (uint8_t*)Dch;  // chart is dead; 32896 B fits easily
  for (int idx = t; idx < 32896; idx += 1024) spl[idx] = SP[idx];
  __syncthreads();
  if (t == 0) {
    int top = 0;
    stk[top++] = (0 << 16) | (n - 1);
    int cnt = 0;
    for (int step = 0; step < n - 1; ++step) {
      if (top > 0) {
        int ij = stk[--top];
        int ii = ij >> 16, jj = ij & 0xffff;
        out[b * n + cnt] = ii;
        out[Bb * n + b * n + cnt] = jj;
        ++cnt;
        int k = jj - ii;
        int s = ii + (int)spl[k * n - ((k * (k - 1)) >> 1) + ii];
        stk[top] = (ii << 16) | s;
        if (s > ii) ++top;
        stk[top] = ((s + 1) << 16) | jj;
        if (jj > s + 1) ++top;
      }
    }
  }
}

// ---------------------------------------------------------------------------
// Launch
// ---------------------------------------------------------------------------
extern "C" void kernel_launch(void* const* d_in, const int* in_sizes, int n_in,
                              void* d_out, int out_size, void* d_ws,
                              size_t ws_size, hipStream_t stream) {
  const float* X = (const float*)d_in[0];     // [64,256,1024]
  const float* Wl = (const float*)d_in[2];    // [1024,1024]
  const float* bl = (const float*)d_in[3];    // [1024]
  const float* Wr = (const float*)d_in[4];
  const float* br = (const float*)d_in[5];
  const float* Wbil = (const float*)d_in[6];  // [1025,1025]
  const float* bbil = (const float*)d_in[7];  // scalar
  int* out = (int*)d_out;

  // workspace layout (floats)
  float* ws = (float*)d_ws;
  const long long NROWS = (long long)Bb * Ss;      // 16384
  float* lefts = ws;                               // 16384x1024
  float* rights = lefts + NROWS * Hh;              // 16384x1024
  float* tmpA = rights + NROWS * Hh;               // 16384x1024
  float* scoresP = tmpA + NROWS * Hh;              // 64x256x256
  float* tmpb = scoresP + (long long)Bb * Ss * Ss; // 16384
  float* Wcore = tmpb + NROWS;                     // 1024x1024
  float* browp = Wcore + (long long)Dd * Hh;       // 1024
  float* bcolp = browp + Hh;                       // 1024
  float* cornerp = bcolp + Hh;                     // 1
  uint8_t* SPp = (uint8_t*)(cornerp + 3);          // 64x32896 u8 (4B aligned)

  repack_kernel<<<dim3(4096), dim3(256), 0, stream>>>(Wbil, Wcore, browp,
                                                      bcolp, cornerp);

  dim3 g1(Hh / 128, NROWS / 128, 1);  // (8,128,1)
  gemm_kernel<false, true><<<g1, 256, 0, stream>>>(
      X, Dd, 0LL, Wl, Hh, 0LL, lefts, Hh, 0LL, bl, nullptr, 0LL, nullptr, Dd);
  gemm_kernel<false, true><<<g1, 256, 0, stream>>>(
      X, Dd, 0LL, Wr, Hh, 0LL, rights, Hh, 0LL, br, nullptr, 0LL, nullptr, Dd);

  colvec_kernel<<<dim3(NROWS), dim3(64), 0, stream>>>(lefts, bcolp, cornerp,
                                                      tmpb);

  gemm_kernel<false, false><<<g1, 256, 0, stream>>>(
      lefts, Hh, 0LL, Wcore, Hh, 0LL, tmpA, Hh, 0LL, browp, nullptr, 0LL,
      nullptr, Hh);

  dim3 g3(Ss / 128, Ss / 128, Bb);  // (2,2,64)
  gemm_kernel<true, false><<<g3, 256, 0, stream>>>(
      tmpA, Hh, (long long)Ss * Hh, rights, Hh, (long long)Ss * Hh, scoresP,
      Ss, (long long)Ss * Ss, nullptr, tmpb, (long long)Ss, bbil, Hh);

  cky_kernel<<<dim3(Bb), dim3(1024), 0, stream>>>(scoresP, SPp, out);
}